// Round 1
// baseline (217.017 us; speedup 1.0000x reference)
//
#include <hip/hip_runtime.h>

// ---------------------------------------------------------------------------
// Res_NL pansharpening network, B=1, H=W=128, f32 in/out. 11 dispatches
// (R11 structure — fusion measured slower). Width over fusion:
//   prep_k     : features 4-way output-split (256 blk) + weight slabs + btab
//                + pad-border zeroing
//   heads_k    : 3 attention heads, 8x4 tiles, 8 threads/pixel
//                (ch-half x d-quarter, shfl-combined), grid (512,3).
//                R12: was 8x8 tiles / 4 thr-px (53us, VALUBusy 8.5%,
//                occupancy ~10% -> latency-bound; this doubles waves and
//                halves the per-thread dependency chain).
//   assemble_k : mlp combine + resu/respan; writes x f32 + padded bf16
//   convm_k    : implicit-GEMM conv, m-tiles split across waves: 384-thr
//                blocks (6 waves = 2 px-halves x 3 oc-tiles), grid 512
//   convr_k    : recon conv 42->8
// Activations padded [42][130][136] u16 (1-halo, 16B-aligned rows).
// ---------------------------------------------------------------------------

#define DEV __device__ __forceinline__
typedef float f32x4 __attribute__((ext_vector_type(4)));
typedef __bf16 bf16x8 __attribute__((ext_vector_type(8)));
typedef unsigned short u16;
typedef unsigned int u32;

constexpr int N = 128 * 128;

// ---- workspace layout (float offsets) -------------------------------------
constexpr int OFF_PHI1 =   0 * N;   // 3 ch
constexpr int OFF_TH1  =   3 * N;   // 3 ch
constexpr int OFF_PHI2 =   6 * N;   // 5 ch
constexpr int OFF_TH2  =  11 * N;   // 5 ch
constexpr int OFF_PHI3 =  16 * N;   // 8 ch
constexpr int OFF_TH3  =  24 * N;   // 8 ch
constexpr int OFF_G1   =  32 * N;   // 5 ch
constexpr int OFF_G2   =  37 * N;   // 5 ch
constexpr int OFF_G3   =  42 * N;   // 5 ch
constexpr int OFF_X    =  47 * N;   // 42 ch f32 (skip path)
constexpr int OFF_OH1  =  89 * N;   // 5 ch
constexpr int OFF_OH2  =  94 * N;   // 5 ch
constexpr int OFF_OH3  =  99 * N;   // 5 ch
constexpr int XPLANE   = 130 * 136;           // 17680 u16 per channel
constexpr int OFF_XPAD = 110 * N;
constexpr int OFF_FPAD = 133 * N;
constexpr int OFF_SLAB = 156 * N;             // u16[116736]
constexpr int OFF_BTAB = 160 * N;             // u16[384]
constexpr int SLAB_RB  = 18432;
constexpr int SLAB_RC  = 110592;
constexpr int SLAB_TOT = 116736;
constexpr int ZPB      = 528;                 // border u16 per plane
constexpr int ZTOT     = 2 * 42 * ZPB;
constexpr int WPREP_TOT = 384 + SLAB_TOT + ZTOT;   // 161472
constexpr int WPREP_BLK = (WPREP_TOT + 255) / 256; // 631

DEV bool inb(int y, int x) { return (unsigned)y < 128u && (unsigned)x < 128u; }
DEV u16 f2bf(float f) {
    unsigned u = __float_as_uint(f);
    return (u16)((u + 0x7fffu + ((u >> 16) & 1u)) >> 16);
}

struct PrepArgs {
    const float* u;    const float* pan;  const float* wnlu; const float* wnlpan;
    const float* gphi; const float* gth;  const float* gg;   const float* sphi;
    const float* sth;  const float* sg;   const float* mphi; const float* mth;
    const float* mg;
    const float* w[7];     // rb0w1,rb0w2,rb1w1,rb1w2,rb2w1,rb2w2,recon
};

// ---------------------------------------------------------------------------
// K1: prep. blocks 0..255: features in 4 output groups (uf conv duplicated,
// latency-bound so duplication ~free, parallelism 2x R11):
//   g0: phi2/th2/g1   g1: g2/g3   g2: phi1/th1/phi3   g3: th3
// blocks 256..: bf16 MFMA A-slabs + btab + pad-border zeroing.
// A per lane: A[m=lane&15][k=(lane>>4)*8+j], k=ic*9+tau.
// btab[k] = ic*120 + (tau/3)*40 + tau%3 (LDS tile row stride 40 u16).
// ---------------------------------------------------------------------------
__global__ __launch_bounds__(256) void prep_k(PrepArgs pa, float* __restrict__ ws,
                                              u16* __restrict__ slab,
                                              u16* __restrict__ btab,
                                              u16* __restrict__ xpad,
                                              u16* __restrict__ fpad) {
    const int bid = blockIdx.x, t = threadIdx.x;
    if (bid < 256) {
        const int g = bid >> 6;
        const int p = (bid & 63) * 256 + t;
        const int y = p >> 7, x = p & 127;

        float uv[8][9];
#pragma unroll
        for (int ic = 0; ic < 8; ++ic)
#pragma unroll
            for (int i = 0; i < 3; ++i)
#pragma unroll
                for (int j = 0; j < 3; ++j) {
                    int yy = y + i - 1, xx = x + j - 1;
                    uv[ic][i * 3 + j] =
                        inb(yy, xx) ? pa.u[ic * N + yy * 128 + xx] : 0.f;
                }
        float uf[5] = {0, 0, 0, 0, 0};
#pragma unroll
        for (int ic = 0; ic < 8; ++ic)
#pragma unroll
            for (int k = 0; k < 9; ++k)
#pragma unroll
                for (int o = 0; o < 5; ++o)
                    uf[o] = fmaf(uv[ic][k], pa.wnlu[(o * 8 + ic) * 9 + k], uf[o]);

        if (g == 0) {
#pragma unroll
            for (int o = 0; o < 5; ++o) {
                float a = 0, b = 0, c1 = 0;
#pragma unroll
                for (int i = 0; i < 5; ++i) {
                    a  = fmaf(pa.sphi[o * 5 + i], uf[i], a);
                    b  = fmaf(pa.sth [o * 5 + i], uf[i], b);
                    c1 = fmaf(pa.gg  [o * 5 + i], uf[i], c1);
                }
                ws[OFF_PHI2 + o * N + p] = a;
                ws[OFF_TH2  + o * N + p] = b;
                ws[OFF_G1   + o * N + p] = c1;
            }
        } else if (g == 1) {
#pragma unroll
            for (int o = 0; o < 5; ++o) {
                float c2 = 0, c3 = 0;
#pragma unroll
                for (int i = 0; i < 5; ++i) {
                    c2 = fmaf(pa.sg[o * 5 + i], uf[i], c2);
                    c3 = fmaf(pa.mg[o * 5 + i], uf[i], c3);
                }
                ws[OFF_G2 + o * N + p] = c2;
                ws[OFF_G3 + o * N + p] = c3;
            }
        } else {
            float pv[9];
#pragma unroll
            for (int i = 0; i < 3; ++i)
#pragma unroll
                for (int j = 0; j < 3; ++j) {
                    int yy = y + i - 1, xx = x + j - 1;
                    pv[i * 3 + j] = inb(yy, xx) ? pa.pan[yy * 128 + xx] : 0.f;
                }
            float pf[3] = {0, 0, 0};
#pragma unroll
            for (int k = 0; k < 9; ++k)
#pragma unroll
                for (int o = 0; o < 3; ++o)
                    pf[o] = fmaf(pv[k], pa.wnlpan[o * 9 + k], pf[o]);
            float cat[8] = {uf[0], uf[1], uf[2], uf[3], uf[4],
                            pf[0], pf[1], pf[2]};
            if (g == 2) {
#pragma unroll
                for (int o = 0; o < 3; ++o) {
                    float a = 0, b = 0;
#pragma unroll
                    for (int i = 0; i < 3; ++i) {
                        a = fmaf(pa.gphi[o * 3 + i], pf[i], a);
                        b = fmaf(pa.gth [o * 3 + i], pf[i], b);
                    }
                    ws[OFF_PHI1 + o * N + p] = a;
                    ws[OFF_TH1  + o * N + p] = b;
                }
#pragma unroll
                for (int o = 0; o < 8; ++o) {
                    float a = 0;
#pragma unroll
                    for (int i = 0; i < 8; ++i)
                        a = fmaf(pa.mphi[o * 8 + i], cat[i], a);
                    ws[OFF_PHI3 + o * N + p] = a;
                }
            } else {
#pragma unroll
                for (int o = 0; o < 8; ++o) {
                    float b = 0;
#pragma unroll
                    for (int i = 0; i < 8; ++i)
                        b = fmaf(pa.mth[o * 8 + i], cat[i], b);
                    ws[OFF_TH3 + o * N + p] = b;
                }
            }
        }
        return;
    }

    int idx = (bid - 256) * 256 + t;
    if (idx >= WPREP_TOT) return;
    if (idx < 384) {
        u16 v = 0;
        if (idx < 378) {
            int ic = idx / 9, tau = idx - ic * 9;
            v = (u16)(ic * 120 + (tau / 3) * 40 + (tau % 3));
        }
        btab[idx] = v;
        return;
    }
    idx -= 384;
    if (idx < SLAB_TOT) {
        const float* W;
        int mt, ks, lane, j, ocv;
        if (idx < SLAB_RC) {
            int cv = idx / SLAB_RB, r = idx - cv * SLAB_RB;
            mt = r / 6144; r -= mt * 6144;
            ks = r / 512;  r -= ks * 512;
            lane = r / 8;  j = r - lane * 8;
            W = pa.w[cv]; ocv = 42;
        } else {
            int r = idx - SLAB_RC;
            mt = 0;
            ks = r / 512;  r -= ks * 512;
            lane = r / 8;  j = r - lane * 8;
            W = pa.w[6]; ocv = 8;
        }
        int k  = ks * 32 + (lane >> 4) * 8 + j;
        int oc = mt * 16 + (lane & 15);
        u16 v = 0;
        if (k < 378 && oc < ocv) {
            int ic = k / 9, tau = k - ic * 9;
            v = f2bf(W[(oc * 42 + ic) * 9 + tau]);
        }
        slab[idx] = v;
        return;
    }
    idx -= SLAB_TOT;
    u16* buf = (idx < 42 * ZPB) ? xpad : fpad;
    int e = (idx < 42 * ZPB) ? idx : idx - 42 * ZPB;
    int plane = e / ZPB, rem = e - plane * ZPB;
    int row, col;
    if (rem < 136)      { row = 0;             col = rem; }
    else if (rem < 272) { row = 129;           col = rem - 136; }
    else if (rem < 400) { row = 1 + rem - 272; col = 0; }
    else                { row = 1 + rem - 400; col = 129; }
    buf[plane * XPLANE + row * 136 + col] = 0;
}

// ---------------------------------------------------------------------------
// K2: attention heads, 8x4 tiles, 256 threads = 8 per pixel:
//   lane bits: [0]=h channel half (score partials, combined via shfl_xor 1)
//              [2:1]=q d-quarter (owns window rows 2q,2q+1; q=3 owns row 6)
//              [5:3]=px, wave=py
// softmax max/sum and PV combined across q via shfl_xor 2,4.
// PV also channel-split: h=0 -> g ch 0..2, h=1 -> ch 3..4.
// phi tile row stride padded (PTWS) + plane padded +1 row so the q-split
// row reads (rows differing by 2) hit distinct banks.
// ---------------------------------------------------------------------------
template <int C, int P>
DEV void head_tile(const float* __restrict__ phi, const float* __restrict__ theta,
                   const float* __restrict__ g, float* __restrict__ oh,
                   float* __restrict__ smem, int ty0, int tx0, int t) {
    constexpr int PR   = P / 2;
    constexpr int H3   = 3 + PR;
    constexpr int W    = 6 + P;
    constexpr int TTH  = 4 + 2 * PR, TTW = 8 + 2 * PR;
    constexpr int PTH  = 4 + 2 * H3, PTW = 8 + 2 * H3;
    constexpr int PTWS = ((PTW + 2) % 4 == 0) ? PTW + 4 : PTW + 2;
    constexpr int PPL  = (PTH + 1) * PTWS;       // padded plane stride
    constexpr int GTH  = 10, GTW = 14;
    constexpr int CH0  = (C + 1) / 2;

    float* sT = smem;
    float* sP = sT + C * TTH * TTW;
    float* sG = sP + C * PPL;

    for (int i = t; i < C * TTH * TTW; i += 256) {
        int c = i / (TTH * TTW), rem = i - c * (TTH * TTW);
        int r = rem / TTW, cc = rem - r * TTW;
        int gy = ty0 - PR + r, gx = tx0 - PR + cc;
        sT[i] = inb(gy, gx) ? theta[c * N + gy * 128 + gx] : 0.f;
    }
    for (int i = t; i < C * PTH * PTW; i += 256) {
        int c = i / (PTH * PTW), rem = i - c * (PTH * PTW);
        int r = rem / PTW, cc = rem - r * PTW;
        int gy = ty0 - H3 + r, gx = tx0 - H3 + cc;
        sP[c * PPL + r * PTWS + cc] = inb(gy, gx) ? phi[c * N + gy * 128 + gx]
                                                  : 0.f;
    }
    for (int i = t; i < 5 * GTH * GTW; i += 256) {
        int c = i / (GTH * GTW), rem = i - c * (GTH * GTW);
        int r = rem / GTW, cc = rem - r * GTW;
        int gy = ty0 - 3 + r, gx = tx0 - 3 + cc;
        sG[i] = inb(gy, gx) ? g[c * N + gy * 128 + gx] : 0.f;
    }
    __syncthreads();

    const int lane = t & 63, wave = t >> 6;
    const int h = lane & 1, q = (lane >> 1) & 3;
    const int px = lane >> 3, py = wave;
    const int gy = ty0 + py, gx = tx0 + px;
    const int dbase = 2 * q;
    const int cbeg = h ? CH0 : 0, cend = h ? C : CH0;

    float s[14];
#pragma unroll
    for (int k = 0; k < 14; ++k) s[k] = 0.f;

#pragma unroll
    for (int ci = 0; ci < CH0; ++ci) {
        int c = cbeg + ci;
        bool cok = c < cend;
        const float* tc = sT + (cok ? c : 0) * TTH * TTW;
        const float* pc = sP + (cok ? c : 0) * PPL;
        float T[P][P];
#pragma unroll
        for (int i = 0; i < P; ++i)
#pragma unroll
            for (int j = 0; j < P; ++j)
                T[i][j] = cok ? tc[(py + i) * TTW + px + j] : 0.f;
        float R[P + 1][W];
#pragma unroll
        for (int r = 0; r <= P; ++r) {
            int rr = py + dbase + r;
            rr = rr < PTH ? rr : PTH - 1;        // q=3,r=P row is dead
#pragma unroll
            for (int w = 0; w < W; ++w)
                R[r][w] = pc[rr * PTWS + px + w];
        }
#pragma unroll
        for (int dd = 0; dd < 2; ++dd)
#pragma unroll
            for (int dx = 0; dx < 7; ++dx) {
                float a = 0.f;
#pragma unroll
                for (int i = 0; i < P; ++i)
#pragma unroll
                    for (int j = 0; j < P; ++j)
                        a = fmaf(T[i][j], R[dd + i][dx + j], a);
                s[dd * 7 + dx] += a;
            }
    }
    // combine channel halves (partner: same pixel/q, other h)
#pragma unroll
    for (int k = 0; k < 14; ++k) s[k] += __shfl_xor(s[k], 1);

#pragma unroll
    for (int k = 0; k < 14; ++k) {
        int d = dbase + k / 7, dx = k % 7;
        if (!inb(gy + d - 3, gx + dx - 3)) s[k] = 0.f;
    }
    const bool own2 = (q < 3);                   // owns k >= 7 (row 2q+1)
    float mx = -3.0e38f;
#pragma unroll
    for (int k = 0; k < 14; ++k) {
        bool own = (k < 7) || own2;
        mx = own ? fmaxf(mx, s[k]) : mx;
    }
    mx = fmaxf(mx, __shfl_xor(mx, 2));
    mx = fmaxf(mx, __shfl_xor(mx, 4));
    float sum = 0.f;
#pragma unroll
    for (int k = 0; k < 14; ++k) {
        bool own = (k < 7) || own2;
        float e = own ? __expf(s[k] - mx) : 0.f;
        s[k] = e;
        sum += e;
    }
    sum += __shfl_xor(sum, 2);
    sum += __shfl_xor(sum, 4);

    // PV, channel-split: h=0 -> g ch 0..2, h=1 -> 3..4
    const int gb = h ? 3 : 0, gn = h ? 2 : 3;
    float o[3] = {0, 0, 0};
#pragma unroll
    for (int k = 0; k < 14; ++k) {
        int d = dbase + k / 7, dx = k % 7;
        int rg = py + d;
        rg = rg < GTH ? rg : GTH - 1;            // dead rows (s[k]==0) only
        int gr = rg * GTW + px + dx;
#pragma unroll
        for (int c5 = 0; c5 < 3; ++c5)
            if (c5 < gn)
                o[c5] = fmaf(s[k], sG[(gb + c5) * GTH * GTW + gr], o[c5]);
    }
#pragma unroll
    for (int c5 = 0; c5 < 3; ++c5) {
        o[c5] += __shfl_xor(o[c5], 2);
        o[c5] += __shfl_xor(o[c5], 4);
    }

    if (q == 0) {
        float inv = 1.f / sum;
        int p = gy * 128 + gx;
#pragma unroll
        for (int c5 = 0; c5 < 3; ++c5)
            if (c5 < gn) oh[(gb + c5) * N + p] = o[c5] * inv;
    }
}

__global__ __launch_bounds__(256, 4) void heads_k(float* __restrict__ ws) {
    __shared__ float smem[3052];   // head3: 480 + 8*234 + 700
    const int t = threadIdx.x;
    const int ty0 = (blockIdx.x >> 4) * 4, tx0 = (blockIdx.x & 15) * 8;
    if (blockIdx.y == 0)
        head_tile<3, 3>(ws + OFF_PHI1, ws + OFF_TH1, ws + OFF_G1, ws + OFF_OH1,
                        smem, ty0, tx0, t);
    else if (blockIdx.y == 1)
        head_tile<5, 1>(ws + OFF_PHI2, ws + OFF_TH2, ws + OFF_G2, ws + OFF_OH2,
                        smem, ty0, tx0, t);
    else
        head_tile<8, 3>(ws + OFF_PHI3, ws + OFF_TH3, ws + OFF_G3, ws + OFF_OH3,
                        smem, ty0, tx0, t);
}

// ---------------------------------------------------------------------------
// K3: assemble, grid (64, 5). Writes x f32 (skip) + padded bf16 (MFMA input).
// ---------------------------------------------------------------------------
__global__ __launch_bounds__(256, 2) void assemble_k(
    const float* __restrict__ u, const float* __restrict__ pan,
    const float* __restrict__ wres, const float* __restrict__ wrp,
    const float* __restrict__ mlpw, const float* __restrict__ mlpb,
    float* __restrict__ ws, u16* __restrict__ xpad) {
    const int p = blockIdx.x * 256 + threadIdx.x;
    const int y = p >> 7, x = p & 127;
    const int padp = (y + 1) * 136 + (x + 1);
    float* xb = ws + OFF_X;

    if (blockIdx.y == 0) {
        const float w0 = mlpw[0], w1 = mlpw[1], w2 = mlpw[2];
        const float bb = mlpb[0];
#pragma unroll
        for (int c = 0; c < 5; ++c) {
            float a = ws[OFF_OH1 + c * N + p] * w0 +
                      ws[OFF_OH2 + c * N + p] * w1 +
                      ws[OFF_OH3 + c * N + p] * w2 + bb;
            xb[c * N + p] = a;
            xpad[c * XPLANE + padp] = f2bf(a);
        }
        float pv[9];
#pragma unroll
        for (int i = 0; i < 3; ++i)
#pragma unroll
            for (int j = 0; j < 3; ++j) {
                int yy = y + i - 1, xx = x + j - 1;
                pv[i * 3 + j] = inb(yy, xx) ? pan[yy * 128 + xx] : 0.f;
            }
        float a5[5] = {0, 0, 0, 0, 0};
#pragma unroll
        for (int k = 0; k < 9; ++k)
#pragma unroll
            for (int o = 0; o < 5; ++o)
                a5[o] = fmaf(pv[k], wrp[o * 9 + k], a5[o]);
#pragma unroll
        for (int o = 0; o < 5; ++o) {
            xb[(37 + o) * N + p] = a5[o];
            xpad[(37 + o) * XPLANE + padp] = f2bf(a5[o]);
        }
    } else {
        const int ob = (blockIdx.y - 1) * 8;
        float uv[8][9];
#pragma unroll
        for (int ic = 0; ic < 8; ++ic)
#pragma unroll
            for (int i = 0; i < 3; ++i)
#pragma unroll
                for (int j = 0; j < 3; ++j) {
                    int yy = y + i - 1, xx = x + j - 1;
                    uv[ic][i * 3 + j] =
                        inb(yy, xx) ? u[ic * N + yy * 128 + xx] : 0.f;
                }
        float acc[8] = {0, 0, 0, 0, 0, 0, 0, 0};
#pragma unroll
        for (int ic = 0; ic < 8; ++ic)
#pragma unroll
            for (int k = 0; k < 9; ++k)
#pragma unroll
                for (int o = 0; o < 8; ++o)
                    acc[o] = fmaf(uv[ic][k], wres[((ob + o) * 8 + ic) * 9 + k],
                                  acc[o]);
#pragma unroll
        for (int o = 0; o < 8; ++o) {
            xb[(5 + ob + o) * N + p] = acc[o];
            xpad[(5 + ob + o) * XPLANE + padp] = f2bf(acc[o]);
        }
    }
}

// ---------------------------------------------------------------------------
// K4: implicit-GEMM conv on MFMA, padded bf16 input. Block = 32 px of one
// row, 384 threads = 6 waves: wave w -> px-half w/3, m-tile w%3.
// 3072 waves total (3/SIMD). Staging 630 uint4, maskless. LDS stride 40 u16.
// Bias+relu always on. D: col=lane&15 (px), row=quad*4+reg (oc).
// ---------------------------------------------------------------------------
template <bool SKIP, bool WF32, bool WPAD>
__global__ __launch_bounds__(384, 3) void convm_k(
    const u16* __restrict__ xin, const u16* __restrict__ slab,
    const u16* __restrict__ btab, const float* __restrict__ bs,
    const float* __restrict__ skip, float* __restrict__ of32,
    u16* __restrict__ opad) {
    __shared__ __align__(16) u16 sX[5040];    // 42*3*40
    __shared__ __align__(16) u16 sBt[384];
    const int t = threadIdx.x;
    const int y = blockIdx.x >> 2, x0 = (blockIdx.x & 3) << 5;

    const u16* srcbase = xin + y * 136 + x0;   // pad rows y..y+2 = img y-1..y+1
#pragma unroll
    for (int it = 0; it < 2; ++it) {
        int c = it * 384 + t;
        if (c < 630) {                         // 126 rows * 5 slots
            int row = c / 5, slot = c - row * 5;
            int ic = row / 3, r = row - ic * 3;
            uint4 v = *((const uint4*)(srcbase + ic * XPLANE + r * 136) + slot);
            *(uint4*)(sX + row * 40 + slot * 8) = v;
        }
    }
    sBt[t >= 384 ? 0 : t] = btab[t >= 384 ? 0 : t];   // t < 384 always
    __syncthreads();

    const int lane = t & 63, wave = t >> 6;
    const int ph = wave / 3, mt = wave - ph * 3;
    const int quad = lane >> 4, col = lane & 15;
    const int ncol = ph * 16 + col;            // 0..31

    union AB { uint4 u; bf16x8 b; };
    AB a[12];
#pragma unroll
    for (int ks = 0; ks < 12; ++ks)
        a[ks].u = ((const uint4*)slab)[(mt * 12 + ks) * 64 + lane];

    f32x4 acc = {0.f, 0.f, 0.f, 0.f};
#pragma unroll
    for (int ks = 0; ks < 12; ++ks) {
        union { uint4 u; u16 s[8]; } off;
        off.u = *(const uint4*)(sBt + ks * 32 + quad * 8);
        union { u16 s[8]; bf16x8 b; } bv;
#pragma unroll
        for (int j = 0; j < 8; ++j) bv.s[j] = sX[off.s[j] + ncol];
        acc = __builtin_amdgcn_mfma_f32_16x16x32_bf16(a[ks].b, bv.b, acc,
                                                      0, 0, 0);
    }

    const int xg = x0 + ncol;
    const int px = y * 128 + xg;
    const int padp = (y + 1) * 136 + (xg + 1);
#pragma unroll
    for (int reg = 0; reg < 4; ++reg) {
        int oc = mt * 16 + quad * 4 + reg;
        if (oc < 42) {
            float v = acc[reg] + bs[oc];
            if (SKIP) v += skip[oc * N + px];
            v = fmaxf(v, 0.f);
            if (WF32) of32[oc * N + px] = v;
            if (WPAD) opad[oc * XPLANE + padp] = f2bf(v);
        }
    }
}

// ---------------------------------------------------------------------------
// K5: recon conv 42->8, padded bf16 input, 32-px strips (grid 512, 128 thr).
// ---------------------------------------------------------------------------
__global__ __launch_bounds__(128, 1) void convr_k(
    const u16* __restrict__ xin, const u16* __restrict__ slab,
    const u16* __restrict__ btab, float* __restrict__ out) {
    __shared__ __align__(16) u16 sX[5040];
    __shared__ __align__(16) u16 sBt[384];
    const int t = threadIdx.x;
    const int y = blockIdx.x >> 2, x0 = (blockIdx.x & 3) << 5;

    const u16* srcbase = xin + y * 136 + x0;
#pragma unroll
    for (int it = 0; it < 5; ++it) {
        int c = it * 128 + t;
        if (c < 630) {
            int row = c / 5, slot = c - row * 5;
            int ic = row / 3, r = row - ic * 3;
            uint4 v = *((const uint4*)(srcbase + ic * XPLANE + r * 136) + slot);
            *(uint4*)(sX + row * 40 + slot * 8) = v;
        }
    }
#pragma unroll
    for (int it = 0; it < 3; ++it) sBt[it * 128 + t] = btab[it * 128 + t];
    __syncthreads();

    const int lane = t & 63, wave = t >> 6;
    const int quad = lane >> 4, col = lane & 15;
    const int ncol = wave * 16 + col;

    union AB { uint4 u; bf16x8 b; };
    AB a[12];
#pragma unroll
    for (int ks = 0; ks < 12; ++ks)
        a[ks].u = ((const uint4*)slab)[ks * 64 + lane];

    f32x4 acc = {0.f, 0.f, 0.f, 0.f};
#pragma unroll
    for (int ks = 0; ks < 12; ++ks) {
        union { uint4 u; u16 s[8]; } off;
        off.u = *(const uint4*)(sBt + ks * 32 + quad * 8);
        union { u16 s[8]; bf16x8 b; } bv;
#pragma unroll
        for (int j = 0; j < 8; ++j) bv.s[j] = sX[off.s[j] + ncol];
        acc = __builtin_amdgcn_mfma_f32_16x16x32_bf16(a[ks].b, bv.b, acc,
                                                      0, 0, 0);
    }
    const int px = y * 128 + x0 + ncol;
#pragma unroll
    for (int reg = 0; reg < 4; ++reg) {
        int oc = quad * 4 + reg;
        if (oc < 8) out[oc * N + px] = acc[reg];
    }
}

// ---------------------------------------------------------------------------
extern "C" void kernel_launch(void* const* d_in, const int* in_sizes, int n_in,
                              void* d_out, int out_size, void* d_ws, size_t ws_size,
                              hipStream_t stream) {
    (void)in_sizes; (void)n_in; (void)out_size; (void)ws_size;
    float* ws = (float*)d_ws;
    float* out = (float*)d_out;

    PrepArgs pa;
    pa.u      = (const float*)d_in[0];
    pa.pan    = (const float*)d_in[1];
    pa.wnlu   = (const float*)d_in[2];
    pa.wnlpan = (const float*)d_in[3];
    pa.gphi   = (const float*)d_in[4];
    pa.gth    = (const float*)d_in[5];
    pa.gg     = (const float*)d_in[6];
    pa.sphi   = (const float*)d_in[7];
    pa.sth    = (const float*)d_in[8];
    pa.sg     = (const float*)d_in[9];
    pa.mphi   = (const float*)d_in[10];
    pa.mth    = (const float*)d_in[11];
    pa.mg     = (const float*)d_in[12];
    pa.w[0]   = (const float*)d_in[18];
    pa.w[1]   = (const float*)d_in[20];
    pa.w[2]   = (const float*)d_in[22];
    pa.w[3]   = (const float*)d_in[24];
    pa.w[4]   = (const float*)d_in[26];
    pa.w[5]   = (const float*)d_in[28];
    pa.w[6]   = (const float*)d_in[17];   // recon

    const float* mlpw = (const float*)d_in[13];
    const float* mlpb = (const float*)d_in[14];
    const float* wres = (const float*)d_in[15];
    const float* wrp  = (const float*)d_in[16];

    u16* xpad = (u16*)(ws + OFF_XPAD);
    u16* fpad = (u16*)(ws + OFF_FPAD);
    u16* slab = (u16*)(ws + OFF_SLAB);
    u16* btab = (u16*)(ws + OFF_BTAB);

    prep_k<<<256 + WPREP_BLK, 256, 0, stream>>>(pa, ws, slab, btab, xpad, fpad);
    heads_k<<<dim3(512, 3), 256, 0, stream>>>(ws);
    assemble_k<<<dim3(64, 5), 256, 0, stream>>>(pa.u, pa.pan, wres, wrp, mlpw,
                                                mlpb, ws, xpad);

    for (int r = 0; r < 3; ++r) {
        const float* b1 = (const float*)d_in[19 + 4 * r];
        const float* b2 = (const float*)d_in[21 + 4 * r];
        convm_k<false, false, true>
            <<<512, 384, 0, stream>>>(xpad, slab + (2 * r) * SLAB_RB, btab, b1,
                                      nullptr, nullptr, fpad);
        convm_k<true, true, true>
            <<<512, 384, 0, stream>>>(fpad, slab + (2 * r + 1) * SLAB_RB, btab,
                                      b2, ws + OFF_X, ws + OFF_X, xpad);
    }
    convr_k<<<512, 128, 0, stream>>>(xpad, slab + SLAB_RC, btab, out);
}

// Round 2
// 216.884 us; speedup vs baseline: 1.0006x; 1.0006x over previous
//
#include <hip/hip_runtime.h>

// ---------------------------------------------------------------------------
// Res_NL pansharpening network, B=1, H=W=128, f32 in/out. 11 dispatches
// (R11 structure — fusion measured slower). Width over fusion:
//   prep_k     : features 4-way output-split (256 blk) + weight slabs
//                + pad-border zeroing
//   heads_k    : 3 attention heads, 8x4 tiles, 8 threads/pixel
//                (ch-half x d-quarter, shfl-combined), grid (512,3). (R12)
//   assemble_k : mlp combine + resu/respan; writes x f32 + padded bf16
//   convm_k    : implicit-GEMM conv, m-tiles split across waves: 384-thr
//                blocks (6 waves = 2 px-halves x 3 oc-tiles), grid 512.
//                R13: K-permuted slab (k -> (g=ic*3+ty, tx)) + pair-dword
//                LDS tile so B-fragments are 4 aligned ds_read_b32 with
//                folded offsets (was 8 scalar u16 + pack per MFMA; gather
//                was the conv bottleneck, 576 ds-ops/blk -> 384, no pack).
//   convr_k    : recon conv 42->8, same scheme
// Activations padded [42][130][136] u16 (1-halo, 16B-aligned rows).
// K-pad: K' = 512 (16 ks); g>=126 rows zeroed in LDS, tx==3 lanes have
// A==0 and read real (finite) data; col 130 zeroed to avoid NaN garbage.
// ---------------------------------------------------------------------------

#define DEV __device__ __forceinline__
typedef float f32x4 __attribute__((ext_vector_type(4)));
typedef __bf16 bf16x8 __attribute__((ext_vector_type(8)));
typedef unsigned short u16;
typedef unsigned int u32;

constexpr int N = 128 * 128;

// ---- workspace layout (float offsets) -------------------------------------
constexpr int OFF_PHI1 =   0 * N;   // 3 ch
constexpr int OFF_TH1  =   3 * N;   // 3 ch
constexpr int OFF_PHI2 =   6 * N;   // 5 ch
constexpr int OFF_TH2  =  11 * N;   // 5 ch
constexpr int OFF_PHI3 =  16 * N;   // 8 ch
constexpr int OFF_TH3  =  24 * N;   // 8 ch
constexpr int OFF_G1   =  32 * N;   // 5 ch
constexpr int OFF_G2   =  37 * N;   // 5 ch
constexpr int OFF_G3   =  42 * N;   // 5 ch
constexpr int OFF_X    =  47 * N;   // 42 ch f32 (skip path)
constexpr int OFF_OH1  =  89 * N;   // 5 ch
constexpr int OFF_OH2  =  94 * N;   // 5 ch
constexpr int OFF_OH3  =  99 * N;   // 5 ch
constexpr int OFF_SLAB = 104 * N;   // u16[155648] in the 104N..110N gap
constexpr int XPLANE   = 130 * 136;           // 17680 u16 per channel
constexpr int OFF_XPAD = 110 * N;
constexpr int OFF_FPAD = 133 * N;
constexpr int SLAB_CV  = 24576;               // u16 per 42-oc conv (3mt*16ks*512)
constexpr int SLAB_RC  = 6 * SLAB_CV;         // 147456 (recon offset)
constexpr int SLAB_TOT = SLAB_RC + 8192;      // 155648
constexpr int ZPB      = 656;                 // border u16 per plane (+col130)
constexpr int ZTOT     = 2 * 42 * ZPB;        // 55104
constexpr int WPREP_TOT = SLAB_TOT + ZTOT;    // 210752
constexpr int WPREP_BLK = (WPREP_TOT + 255) / 256; // 824

DEV bool inb(int y, int x) { return (unsigned)y < 128u && (unsigned)x < 128u; }
DEV u16 f2bf(float f) {
    unsigned u = __float_as_uint(f);
    return (u16)((u + 0x7fffu + ((u >> 16) & 1u)) >> 16);
}

struct PrepArgs {
    const float* u;    const float* pan;  const float* wnlu; const float* wnlpan;
    const float* gphi; const float* gth;  const float* gg;   const float* sphi;
    const float* sth;  const float* sg;   const float* mphi; const float* mth;
    const float* mg;
    const float* w[7];     // rb0w1,rb0w2,rb1w1,rb1w2,rb2w1,rb2w2,recon
};

// ---------------------------------------------------------------------------
// K1: prep. blocks 0..255: features in 4 output groups.
// blocks 256..: bf16 MFMA A-slabs + pad-border zeroing.
// Slab K-permutation (R13): k = ks*32 + quad*8 + j, with
//   g  = ks*8 + quad*2 + (j>>2)   (g = ic*3 + ty, input row id, <126 valid)
//   tx = j&3                      (window col, tx==3 -> A=0 pad)
// A[k][oc=mt*16+m] per lane (m=lane&15, quad=lane>>4) as uint4 of 8 bf16.
// ---------------------------------------------------------------------------
__global__ __launch_bounds__(256) void prep_k(PrepArgs pa, float* __restrict__ ws,
                                              u16* __restrict__ slab,
                                              u16* __restrict__ xpad,
                                              u16* __restrict__ fpad) {
    const int bid = blockIdx.x, t = threadIdx.x;
    if (bid < 256) {
        const int g = bid >> 6;
        const int p = (bid & 63) * 256 + t;
        const int y = p >> 7, x = p & 127;

        float uv[8][9];
#pragma unroll
        for (int ic = 0; ic < 8; ++ic)
#pragma unroll
            for (int i = 0; i < 3; ++i)
#pragma unroll
                for (int j = 0; j < 3; ++j) {
                    int yy = y + i - 1, xx = x + j - 1;
                    uv[ic][i * 3 + j] =
                        inb(yy, xx) ? pa.u[ic * N + yy * 128 + xx] : 0.f;
                }
        float uf[5] = {0, 0, 0, 0, 0};
#pragma unroll
        for (int ic = 0; ic < 8; ++ic)
#pragma unroll
            for (int k = 0; k < 9; ++k)
#pragma unroll
                for (int o = 0; o < 5; ++o)
                    uf[o] = fmaf(uv[ic][k], pa.wnlu[(o * 8 + ic) * 9 + k], uf[o]);

        if (g == 0) {
#pragma unroll
            for (int o = 0; o < 5; ++o) {
                float a = 0, b = 0, c1 = 0;
#pragma unroll
                for (int i = 0; i < 5; ++i) {
                    a  = fmaf(pa.sphi[o * 5 + i], uf[i], a);
                    b  = fmaf(pa.sth [o * 5 + i], uf[i], b);
                    c1 = fmaf(pa.gg  [o * 5 + i], uf[i], c1);
                }
                ws[OFF_PHI2 + o * N + p] = a;
                ws[OFF_TH2  + o * N + p] = b;
                ws[OFF_G1   + o * N + p] = c1;
            }
        } else if (g == 1) {
#pragma unroll
            for (int o = 0; o < 5; ++o) {
                float c2 = 0, c3 = 0;
#pragma unroll
                for (int i = 0; i < 5; ++i) {
                    c2 = fmaf(pa.sg[o * 5 + i], uf[i], c2);
                    c3 = fmaf(pa.mg[o * 5 + i], uf[i], c3);
                }
                ws[OFF_G2 + o * N + p] = c2;
                ws[OFF_G3 + o * N + p] = c3;
            }
        } else {
            float pv[9];
#pragma unroll
            for (int i = 0; i < 3; ++i)
#pragma unroll
                for (int j = 0; j < 3; ++j) {
                    int yy = y + i - 1, xx = x + j - 1;
                    pv[i * 3 + j] = inb(yy, xx) ? pa.pan[yy * 128 + xx] : 0.f;
                }
            float pf[3] = {0, 0, 0};
#pragma unroll
            for (int k = 0; k < 9; ++k)
#pragma unroll
                for (int o = 0; o < 3; ++o)
                    pf[o] = fmaf(pv[k], pa.wnlpan[o * 9 + k], pf[o]);
            float cat[8] = {uf[0], uf[1], uf[2], uf[3], uf[4],
                            pf[0], pf[1], pf[2]};
            if (g == 2) {
#pragma unroll
                for (int o = 0; o < 3; ++o) {
                    float a = 0, b = 0;
#pragma unroll
                    for (int i = 0; i < 3; ++i) {
                        a = fmaf(pa.gphi[o * 3 + i], pf[i], a);
                        b = fmaf(pa.gth [o * 3 + i], pf[i], b);
                    }
                    ws[OFF_PHI1 + o * N + p] = a;
                    ws[OFF_TH1  + o * N + p] = b;
                }
#pragma unroll
                for (int o = 0; o < 8; ++o) {
                    float a = 0;
#pragma unroll
                    for (int i = 0; i < 8; ++i)
                        a = fmaf(pa.mphi[o * 8 + i], cat[i], a);
                    ws[OFF_PHI3 + o * N + p] = a;
                }
            } else {
#pragma unroll
                for (int o = 0; o < 8; ++o) {
                    float b = 0;
#pragma unroll
                    for (int i = 0; i < 8; ++i)
                        b = fmaf(pa.mth[o * 8 + i], cat[i], b);
                    ws[OFF_TH3 + o * N + p] = b;
                }
            }
        }
        return;
    }

    int idx = (bid - 256) * 256 + t;
    if (idx >= WPREP_TOT) return;
    if (idx < SLAB_TOT) {
        const float* W;
        int mt, ks, lane, j, ocv;
        if (idx < SLAB_RC) {
            int cv = idx / SLAB_CV, r = idx - cv * SLAB_CV;
            mt = r / 8192;  r -= mt * 8192;
            ks = r / 512;   r -= ks * 512;
            lane = r / 8;   j = r - lane * 8;
            W = pa.w[cv]; ocv = 42;
        } else {
            int r = idx - SLAB_RC;
            mt = 0;
            ks = r / 512;   r -= ks * 512;
            lane = r / 8;   j = r - lane * 8;
            W = pa.w[6]; ocv = 8;
        }
        int quad = lane >> 4, m = lane & 15;
        int g = ks * 8 + quad * 2 + (j >> 2), tx = j & 3;
        int oc = mt * 16 + m;
        u16 v = 0;
        if (g < 126 && tx < 3 && oc < ocv) {
            int ic = g / 3, ty = g - ic * 3;
            v = f2bf(W[(oc * 42 + ic) * 9 + ty * 3 + tx]);
        }
        slab[idx] = v;
        return;
    }
    idx -= SLAB_TOT;
    u16* buf = (idx < 42 * ZPB) ? xpad : fpad;
    int e = (idx < 42 * ZPB) ? idx : idx - 42 * ZPB;
    int plane = e / ZPB, rem = e - plane * ZPB;
    int row, col;
    if (rem < 136)      { row = 0;             col = rem; }
    else if (rem < 272) { row = 129;           col = rem - 136; }
    else if (rem < 400) { row = 1 + rem - 272; col = 0; }
    else if (rem < 528) { row = 1 + rem - 400; col = 129; }
    else                { row = 1 + rem - 528; col = 130; }
    buf[plane * XPLANE + row * 136 + col] = 0;
}

// ---------------------------------------------------------------------------
// K2: attention heads, 8x4 tiles, 256 threads = 8 per pixel:
//   lane bits: [0]=h channel half (score partials, combined via shfl_xor 1)
//              [2:1]=q d-quarter (owns window rows 2q,2q+1; q=3 owns row 6)
//              [5:3]=px, wave=py
// softmax max/sum and PV combined across q via shfl_xor 2,4.
// PV also channel-split: h=0 -> g ch 0..2, h=1 -> ch 3..4.
// ---------------------------------------------------------------------------
template <int C, int P>
DEV void head_tile(const float* __restrict__ phi, const float* __restrict__ theta,
                   const float* __restrict__ g, float* __restrict__ oh,
                   float* __restrict__ smem, int ty0, int tx0, int t) {
    constexpr int PR   = P / 2;
    constexpr int H3   = 3 + PR;
    constexpr int W    = 6 + P;
    constexpr int TTH  = 4 + 2 * PR, TTW = 8 + 2 * PR;
    constexpr int PTH  = 4 + 2 * H3, PTW = 8 + 2 * H3;
    constexpr int PTWS = ((PTW + 2) % 4 == 0) ? PTW + 4 : PTW + 2;
    constexpr int PPL  = (PTH + 1) * PTWS;       // padded plane stride
    constexpr int GTH  = 10, GTW = 14;
    constexpr int CH0  = (C + 1) / 2;

    float* sT = smem;
    float* sP = sT + C * TTH * TTW;
    float* sG = sP + C * PPL;

    for (int i = t; i < C * TTH * TTW; i += 256) {
        int c = i / (TTH * TTW), rem = i - c * (TTH * TTW);
        int r = rem / TTW, cc = rem - r * TTW;
        int gy = ty0 - PR + r, gx = tx0 - PR + cc;
        sT[i] = inb(gy, gx) ? theta[c * N + gy * 128 + gx] : 0.f;
    }
    for (int i = t; i < C * PTH * PTW; i += 256) {
        int c = i / (PTH * PTW), rem = i - c * (PTH * PTW);
        int r = rem / PTW, cc = rem - r * PTW;
        int gy = ty0 - H3 + r, gx = tx0 - H3 + cc;
        sP[c * PPL + r * PTWS + cc] = inb(gy, gx) ? phi[c * N + gy * 128 + gx]
                                                  : 0.f;
    }
    for (int i = t; i < 5 * GTH * GTW; i += 256) {
        int c = i / (GTH * GTW), rem = i - c * (GTH * GTW);
        int r = rem / GTW, cc = rem - r * GTW;
        int gy = ty0 - 3 + r, gx = tx0 - 3 + cc;
        sG[i] = inb(gy, gx) ? g[c * N + gy * 128 + gx] : 0.f;
    }
    __syncthreads();

    const int lane = t & 63, wave = t >> 6;
    const int h = lane & 1, q = (lane >> 1) & 3;
    const int px = lane >> 3, py = wave;
    const int gy = ty0 + py, gx = tx0 + px;
    const int dbase = 2 * q;
    const int cbeg = h ? CH0 : 0, cend = h ? C : CH0;

    float s[14];
#pragma unroll
    for (int k = 0; k < 14; ++k) s[k] = 0.f;

#pragma unroll
    for (int ci = 0; ci < CH0; ++ci) {
        int c = cbeg + ci;
        bool cok = c < cend;
        const float* tc = sT + (cok ? c : 0) * TTH * TTW;
        const float* pc = sP + (cok ? c : 0) * PPL;
        float T[P][P];
#pragma unroll
        for (int i = 0; i < P; ++i)
#pragma unroll
            for (int j = 0; j < P; ++j)
                T[i][j] = cok ? tc[(py + i) * TTW + px + j] : 0.f;
        float R[P + 1][W];
#pragma unroll
        for (int r = 0; r <= P; ++r) {
            int rr = py + dbase + r;
            rr = rr < PTH ? rr : PTH - 1;        // q=3,r=P row is dead
#pragma unroll
            for (int w = 0; w < W; ++w)
                R[r][w] = pc[rr * PTWS + px + w];
        }
#pragma unroll
        for (int dd = 0; dd < 2; ++dd)
#pragma unroll
            for (int dx = 0; dx < 7; ++dx) {
                float a = 0.f;
#pragma unroll
                for (int i = 0; i < P; ++i)
#pragma unroll
                    for (int j = 0; j < P; ++j)
                        a = fmaf(T[i][j], R[dd + i][dx + j], a);
                s[dd * 7 + dx] += a;
            }
    }
    // combine channel halves (partner: same pixel/q, other h)
#pragma unroll
    for (int k = 0; k < 14; ++k) s[k] += __shfl_xor(s[k], 1);

#pragma unroll
    for (int k = 0; k < 14; ++k) {
        int d = dbase + k / 7, dx = k % 7;
        if (!inb(gy + d - 3, gx + dx - 3)) s[k] = 0.f;
    }
    const bool own2 = (q < 3);                   // owns k >= 7 (row 2q+1)
    float mx = -3.0e38f;
#pragma unroll
    for (int k = 0; k < 14; ++k) {
        bool own = (k < 7) || own2;
        mx = own ? fmaxf(mx, s[k]) : mx;
    }
    mx = fmaxf(mx, __shfl_xor(mx, 2));
    mx = fmaxf(mx, __shfl_xor(mx, 4));
    float sum = 0.f;
#pragma unroll
    for (int k = 0; k < 14; ++k) {
        bool own = (k < 7) || own2;
        float e = own ? __expf(s[k] - mx) : 0.f;
        s[k] = e;
        sum += e;
    }
    sum += __shfl_xor(sum, 2);
    sum += __shfl_xor(sum, 4);

    // PV, channel-split: h=0 -> g ch 0..2, h=1 -> 3..4
    const int gb = h ? 3 : 0, gn = h ? 2 : 3;
    float o[3] = {0, 0, 0};
#pragma unroll
    for (int k = 0; k < 14; ++k) {
        int d = dbase + k / 7, dx = k % 7;
        int rg = py + d;
        rg = rg < GTH ? rg : GTH - 1;            // dead rows (s[k]==0) only
        int gr = rg * GTW + px + dx;
#pragma unroll
        for (int c5 = 0; c5 < 3; ++c5)
            if (c5 < gn)
                o[c5] = fmaf(s[k], sG[(gb + c5) * GTH * GTW + gr], o[c5]);
    }
#pragma unroll
    for (int c5 = 0; c5 < 3; ++c5) {
        o[c5] += __shfl_xor(o[c5], 2);
        o[c5] += __shfl_xor(o[c5], 4);
    }

    if (q == 0) {
        float inv = 1.f / sum;
        int p = gy * 128 + gx;
#pragma unroll
        for (int c5 = 0; c5 < 3; ++c5)
            if (c5 < gn) oh[(gb + c5) * N + p] = o[c5] * inv;
    }
}

__global__ __launch_bounds__(256, 4) void heads_k(float* __restrict__ ws) {
    __shared__ float smem[3052];   // head3: 480 + 8*234 + 700
    const int t = threadIdx.x;
    const int ty0 = (blockIdx.x >> 4) * 4, tx0 = (blockIdx.x & 15) * 8;
    if (blockIdx.y == 0)
        head_tile<3, 3>(ws + OFF_PHI1, ws + OFF_TH1, ws + OFF_G1, ws + OFF_OH1,
                        smem, ty0, tx0, t);
    else if (blockIdx.y == 1)
        head_tile<5, 1>(ws + OFF_PHI2, ws + OFF_TH2, ws + OFF_G2, ws + OFF_OH2,
                        smem, ty0, tx0, t);
    else
        head_tile<8, 3>(ws + OFF_PHI3, ws + OFF_TH3, ws + OFF_G3, ws + OFF_OH3,
                        smem, ty0, tx0, t);
}

// ---------------------------------------------------------------------------
// K3: assemble, grid (64, 5). Writes x f32 (skip) + padded bf16 (MFMA input).
// ---------------------------------------------------------------------------
__global__ __launch_bounds__(256, 2) void assemble_k(
    const float* __restrict__ u, const float* __restrict__ pan,
    const float* __restrict__ wres, const float* __restrict__ wrp,
    const float* __restrict__ mlpw, const float* __restrict__ mlpb,
    float* __restrict__ ws, u16* __restrict__ xpad) {
    const int p = blockIdx.x * 256 + threadIdx.x;
    const int y = p >> 7, x = p & 127;
    const int padp = (y + 1) * 136 + (x + 1);
    float* xb = ws + OFF_X;

    if (blockIdx.y == 0) {
        const float w0 = mlpw[0], w1 = mlpw[1], w2 = mlpw[2];
        const float bb = mlpb[0];
#pragma unroll
        for (int c = 0; c < 5; ++c) {
            float a = ws[OFF_OH1 + c * N + p] * w0 +
                      ws[OFF_OH2 + c * N + p] * w1 +
                      ws[OFF_OH3 + c * N + p] * w2 + bb;
            xb[c * N + p] = a;
            xpad[c * XPLANE + padp] = f2bf(a);
        }
        float pv[9];
#pragma unroll
        for (int i = 0; i < 3; ++i)
#pragma unroll
            for (int j = 0; j < 3; ++j) {
                int yy = y + i - 1, xx = x + j - 1;
                pv[i * 3 + j] = inb(yy, xx) ? pan[yy * 128 + xx] : 0.f;
            }
        float a5[5] = {0, 0, 0, 0, 0};
#pragma unroll
        for (int k = 0; k < 9; ++k)
#pragma unroll
            for (int o = 0; o < 5; ++o)
                a5[o] = fmaf(pv[k], wrp[o * 9 + k], a5[o]);
#pragma unroll
        for (int o = 0; o < 5; ++o) {
            xb[(37 + o) * N + p] = a5[o];
            xpad[(37 + o) * XPLANE + padp] = f2bf(a5[o]);
        }
    } else {
        const int ob = (blockIdx.y - 1) * 8;
        float uv[8][9];
#pragma unroll
        for (int ic = 0; ic < 8; ++ic)
#pragma unroll
            for (int i = 0; i < 3; ++i)
#pragma unroll
                for (int j = 0; j < 3; ++j) {
                    int yy = y + i - 1, xx = x + j - 1;
                    uv[ic][i * 3 + j] =
                        inb(yy, xx) ? u[ic * N + yy * 128 + xx] : 0.f;
                }
        float acc[8] = {0, 0, 0, 0, 0, 0, 0, 0};
#pragma unroll
        for (int ic = 0; ic < 8; ++ic)
#pragma unroll
            for (int k = 0; k < 9; ++k)
#pragma unroll
                for (int o = 0; o < 8; ++o)
                    acc[o] = fmaf(uv[ic][k], wres[((ob + o) * 8 + ic) * 9 + k],
                                  acc[o]);
#pragma unroll
        for (int o = 0; o < 8; ++o) {
            xb[(5 + ob + o) * N + p] = acc[o];
            xpad[(5 + ob + o) * XPLANE + padp] = f2bf(acc[o]);
        }
    }
}

// ---------------------------------------------------------------------------
// K4: implicit-GEMM conv on MFMA, padded bf16 input. Block = 32 px of one
// row, 384 threads = 6 waves: wave w -> px-half w/3, m-tile w%3.
// R13 pair-dword LDS tile: sXp[g][x] = (v[x], v[x+1]) packed u32, g=ic*3+ty
// row (stride 40 dw). B-fragment for ks: 4 ds_read_b32 at
// base + ks*320 dw + {0,2,40,42} (compiler folds to ds_read2_b32, 2-way
// banks). 16 MFMA/wave (K'=512). Bias+relu always on.
// D: col=lane&15 (px), row=quad*4+reg (oc).
// ---------------------------------------------------------------------------
template <bool SKIP, bool WF32, bool WPAD>
__global__ __launch_bounds__(384, 3) void convm_k(
    const u16* __restrict__ xin, const u16* __restrict__ slab,
    const float* __restrict__ bs, const float* __restrict__ skip,
    float* __restrict__ of32, u16* __restrict__ opad) {
    __shared__ __align__(16) u32 sXp[5120];   // 128 g-rows x 40 pair-dwords
    const int t = threadIdx.x;
    const int y = blockIdx.x >> 2, x0 = (blockIdx.x & 3) << 5;

    const u16* srcbase = xin + y * 136 + x0;   // pad rows y..y+2 = img y-1..y+1
#pragma unroll
    for (int it = 0; it < 2; ++it) {
        int c = it * 384 + t;
        if (c < 630) {                         // 126 rows * 5 slots
            int row = c / 5, slot = c - row * 5;
            int ic = row / 3, r = row - ic * 3;
            const u16* sp = srcbase + ic * XPLANE + r * 136 + slot * 8;
            uint4 v = *(const uint4*)sp;
            u32 nxt = sp[8];
            u32 d0 = v.x, d1 = v.y, d2 = v.z, d3 = v.w;
            uint4 w0, w1;
            w0.x = d0; w0.y = (d0 >> 16) | (d1 << 16);
            w0.z = d1; w0.w = (d1 >> 16) | (d2 << 16);
            w1.x = d2; w1.y = (d2 >> 16) | (d3 << 16);
            w1.z = d3; w1.w = (d3 >> 16) | (nxt << 16);
            u32* dst = sXp + row * 40 + slot * 8;
            *(uint4*)dst = w0;
            *(uint4*)(dst + 4) = w1;
        }
    }
    if (t < 80) sXp[5040 + t] = 0;             // g=126,127 pad rows
    __syncthreads();

    const int lane = t & 63, wave = t >> 6;
    const int ph = wave / 3, mt = wave - ph * 3;
    const int quad = lane >> 4, col = lane & 15;
    const int ncol = ph * 16 + col;            // 0..31

    union AB { uint4 u; bf16x8 b; };
    AB a[16];
#pragma unroll
    for (int ks = 0; ks < 16; ++ks)
        a[ks].u = ((const uint4*)slab)[(mt * 16 + ks) * 64 + lane];

    const u32* bb = sXp + quad * 80 + ncol;
    f32x4 acc = {0.f, 0.f, 0.f, 0.f};
#pragma unroll
    for (int ks = 0; ks < 16; ++ks) {
        union { uint4 u; bf16x8 b; } bv;
        const u32* pb = bb + ks * 320;
        bv.u.x = pb[0]; bv.u.y = pb[2]; bv.u.z = pb[40]; bv.u.w = pb[42];
        acc = __builtin_amdgcn_mfma_f32_16x16x32_bf16(a[ks].b, bv.b, acc,
                                                      0, 0, 0);
    }

    const int xg = x0 + ncol;
    const int px = y * 128 + xg;
    const int padp = (y + 1) * 136 + (xg + 1);
#pragma unroll
    for (int reg = 0; reg < 4; ++reg) {
        int oc = mt * 16 + quad * 4 + reg;
        if (oc < 42) {
            float v = acc[reg] + bs[oc];
            if (SKIP) v += skip[oc * N + px];
            v = fmaxf(v, 0.f);
            if (WF32) of32[oc * N + px] = v;
            if (WPAD) opad[oc * XPLANE + padp] = f2bf(v);
        }
    }
}

// ---------------------------------------------------------------------------
// K5: recon conv 42->8, padded bf16 input, 32-px strips (grid 512, 128 thr).
// Same R13 pair-dword scheme, mt=0.
// ---------------------------------------------------------------------------
__global__ __launch_bounds__(128, 1) void convr_k(
    const u16* __restrict__ xin, const u16* __restrict__ slab,
    float* __restrict__ out) {
    __shared__ __align__(16) u32 sXp[5120];
    const int t = threadIdx.x;
    const int y = blockIdx.x >> 2, x0 = (blockIdx.x & 3) << 5;

    const u16* srcbase = xin + y * 136 + x0;
#pragma unroll
    for (int it = 0; it < 5; ++it) {
        int c = it * 128 + t;
        if (c < 630) {
            int row = c / 5, slot = c - row * 5;
            int ic = row / 3, r = row - ic * 3;
            const u16* sp = srcbase + ic * XPLANE + r * 136 + slot * 8;
            uint4 v = *(const uint4*)sp;
            u32 nxt = sp[8];
            u32 d0 = v.x, d1 = v.y, d2 = v.z, d3 = v.w;
            uint4 w0, w1;
            w0.x = d0; w0.y = (d0 >> 16) | (d1 << 16);
            w0.z = d1; w0.w = (d1 >> 16) | (d2 << 16);
            w1.x = d2; w1.y = (d2 >> 16) | (d3 << 16);
            w1.z = d3; w1.w = (d3 >> 16) | (nxt << 16);
            u32* dst = sXp + row * 40 + slot * 8;
            *(uint4*)dst = w0;
            *(uint4*)(dst + 4) = w1;
        }
    }
    if (t < 80) sXp[5040 + t] = 0;
    __syncthreads();

    const int lane = t & 63, wave = t >> 6;
    const int quad = lane >> 4, col = lane & 15;
    const int ncol = wave * 16 + col;

    union AB { uint4 u; bf16x8 b; };
    AB a[16];
#pragma unroll
    for (int ks = 0; ks < 16; ++ks)
        a[ks].u = ((const uint4*)slab)[ks * 64 + lane];

    const u32* bb = sXp + quad * 80 + ncol;
    f32x4 acc = {0.f, 0.f, 0.f, 0.f};
#pragma unroll
    for (int ks = 0; ks < 16; ++ks) {
        union { uint4 u; bf16x8 b; } bv;
        const u32* pb = bb + ks * 320;
        bv.u.x = pb[0]; bv.u.y = pb[2]; bv.u.z = pb[40]; bv.u.w = pb[42];
        acc = __builtin_amdgcn_mfma_f32_16x16x32_bf16(a[ks].b, bv.b, acc,
                                                      0, 0, 0);
    }
    const int px = y * 128 + x0 + ncol;
#pragma unroll
    for (int reg = 0; reg < 4; ++reg) {
        int oc = quad * 4 + reg;
        if (oc < 8) out[oc * N + px] = acc[reg];
    }
}

// ---------------------------------------------------------------------------
extern "C" void kernel_launch(void* const* d_in, const int* in_sizes, int n_in,
                              void* d_out, int out_size, void* d_ws, size_t ws_size,
                              hipStream_t stream) {
    (void)in_sizes; (void)n_in; (void)out_size; (void)ws_size;
    float* ws = (float*)d_ws;
    float* out = (float*)d_out;

    PrepArgs pa;
    pa.u      = (const float*)d_in[0];
    pa.pan    = (const float*)d_in[1];
    pa.wnlu   = (const float*)d_in[2];
    pa.wnlpan = (const float*)d_in[3];
    pa.gphi   = (const float*)d_in[4];
    pa.gth    = (const float*)d_in[5];
    pa.gg     = (const float*)d_in[6];
    pa.sphi   = (const float*)d_in[7];
    pa.sth    = (const float*)d_in[8];
    pa.sg     = (const float*)d_in[9];
    pa.mphi   = (const float*)d_in[10];
    pa.mth    = (const float*)d_in[11];
    pa.mg     = (const float*)d_in[12];
    pa.w[0]   = (const float*)d_in[18];
    pa.w[1]   = (const float*)d_in[20];
    pa.w[2]   = (const float*)d_in[22];
    pa.w[3]   = (const float*)d_in[24];
    pa.w[4]   = (const float*)d_in[26];
    pa.w[5]   = (const float*)d_in[28];
    pa.w[6]   = (const float*)d_in[17];   // recon

    const float* mlpw = (const float*)d_in[13];
    const float* mlpb = (const float*)d_in[14];
    const float* wres = (const float*)d_in[15];
    const float* wrp  = (const float*)d_in[16];

    u16* xpad = (u16*)(ws + OFF_XPAD);
    u16* fpad = (u16*)(ws + OFF_FPAD);
    u16* slab = (u16*)(ws + OFF_SLAB);

    prep_k<<<256 + WPREP_BLK, 256, 0, stream>>>(pa, ws, slab, xpad, fpad);
    heads_k<<<dim3(512, 3), 256, 0, stream>>>(ws);
    assemble_k<<<dim3(64, 5), 256, 0, stream>>>(pa.u, pa.pan, wres, wrp, mlpw,
                                                mlpb, ws, xpad);

    for (int r = 0; r < 3; ++r) {
        const float* b1 = (const float*)d_in[19 + 4 * r];
        const float* b2 = (const float*)d_in[21 + 4 * r];
        convm_k<false, false, true>
            <<<512, 384, 0, stream>>>(xpad, slab + (2 * r) * SLAB_CV, b1,
                                      nullptr, nullptr, fpad);
        convm_k<true, true, true>
            <<<512, 384, 0, stream>>>(fpad, slab + (2 * r + 1) * SLAB_CV, b2,
                                      ws + OFF_X, ws + OFF_X, xpad);
    }
    convr_k<<<512, 128, 0, stream>>>(xpad, slab + SLAB_RC, out);
}

// Round 3
// 209.140 us; speedup vs baseline: 1.0377x; 1.0370x over previous
//
#include <hip/hip_runtime.h>

// ---------------------------------------------------------------------------
// Res_NL pansharpening network, B=1, H=W=128, f32 in/out. 11 dispatches.
//   prep_k     : features 4-way output-split (256 blk) + weight slabs
//                + pad-border zeroing
//   heads_k    : R14: attention heads on MFMA. Per 8x8-px tile:
//                S[64][224] = thp(64xK') x php(K'x224) via 16x16x32 bf16 MFMA
//                (nbhd = 14 rows x 16 cols padded, n = r*16+c').
//                php im2col'd to LDS [n][k] rows (B-frag = 1 ds_read_b128),
//                thp gathered to regs. Softmax in C-layout regs (window mask;
//                OOB px' give score 0 via zero-staged phi = reference
//                zero-pad semantics). PV scalar from LDS g + shfl reduce.
//   assemble_k : mlp combine + resu/respan; writes x f32 + padded bf16
//   convm_k    : implicit-GEMM conv. R14: 1024 blocks x 192 thr (16-px
//                strips, 3 waves = 3 oc-tiles) -> 4 blocks/CU (was 2,
//                latency-bound). Pair-dword LDS tile stride 24.
//   convr_k    : recon conv 42->8 (unchanged, 512x128)
// Activations padded [42][130][136] u16 (1-halo, 16B-aligned rows).
// ---------------------------------------------------------------------------

#define DEV __device__ __forceinline__
typedef float f32x4 __attribute__((ext_vector_type(4)));
typedef __bf16 bf16x8 __attribute__((ext_vector_type(8)));
typedef unsigned short u16;
typedef unsigned int u32;

constexpr int N = 128 * 128;

// ---- workspace layout (float offsets) -------------------------------------
constexpr int OFF_PHI1 =   0 * N;   // 3 ch
constexpr int OFF_TH1  =   3 * N;   // 3 ch
constexpr int OFF_PHI2 =   6 * N;   // 5 ch
constexpr int OFF_TH2  =  11 * N;   // 5 ch
constexpr int OFF_PHI3 =  16 * N;   // 8 ch
constexpr int OFF_TH3  =  24 * N;   // 8 ch
constexpr int OFF_G1   =  32 * N;   // 5 ch
constexpr int OFF_G2   =  37 * N;   // 5 ch
constexpr int OFF_G3   =  42 * N;   // 5 ch
constexpr int OFF_X    =  47 * N;   // 42 ch f32 (skip path)
constexpr int OFF_OH1  =  89 * N;   // 5 ch
constexpr int OFF_OH2  =  94 * N;   // 5 ch
constexpr int OFF_OH3  =  99 * N;   // 5 ch
constexpr int OFF_SLAB = 104 * N;   // u16[155648] in the 104N..110N gap
constexpr int XPLANE   = 130 * 136;           // 17680 u16 per channel
constexpr int OFF_XPAD = 110 * N;
constexpr int OFF_FPAD = 133 * N;
constexpr int SLAB_CV  = 24576;               // u16 per 42-oc conv (3mt*16ks*512)
constexpr int SLAB_RC  = 6 * SLAB_CV;         // 147456 (recon offset)
constexpr int SLAB_TOT = SLAB_RC + 8192;      // 155648
constexpr int ZPB      = 656;                 // border u16 per plane (+col130)
constexpr int ZTOT     = 2 * 42 * ZPB;        // 55104
constexpr int WPREP_TOT = SLAB_TOT + ZTOT;    // 210752
constexpr int WPREP_BLK = (WPREP_TOT + 255) / 256; // 824

DEV bool inb(int y, int x) { return (unsigned)y < 128u && (unsigned)x < 128u; }
DEV u16 f2bf(float f) {
    unsigned u = __float_as_uint(f);
    return (u16)((u + 0x7fffu + ((u >> 16) & 1u)) >> 16);
}

struct PrepArgs {
    const float* u;    const float* pan;  const float* wnlu; const float* wnlpan;
    const float* gphi; const float* gth;  const float* gg;   const float* sphi;
    const float* sth;  const float* sg;   const float* mphi; const float* mth;
    const float* mg;
    const float* w[7];     // rb0w1,rb0w2,rb1w1,rb1w2,rb2w1,rb2w2,recon
};

// ---------------------------------------------------------------------------
// K1: prep. blocks 0..255: features in 4 output groups.
// blocks 256..: bf16 MFMA A-slabs + pad-border zeroing.
// Slab K-permutation: k = ks*32 + quad*8 + j, with
//   g  = ks*8 + quad*2 + (j>>2)   (g = ic*3 + ty, input row id, <126 valid)
//   tx = j&3                      (window col, tx==3 -> A=0 pad)
// ---------------------------------------------------------------------------
__global__ __launch_bounds__(256) void prep_k(PrepArgs pa, float* __restrict__ ws,
                                              u16* __restrict__ slab,
                                              u16* __restrict__ xpad,
                                              u16* __restrict__ fpad) {
    const int bid = blockIdx.x, t = threadIdx.x;
    if (bid < 256) {
        const int g = bid >> 6;
        const int p = (bid & 63) * 256 + t;
        const int y = p >> 7, x = p & 127;

        float uv[8][9];
#pragma unroll
        for (int ic = 0; ic < 8; ++ic)
#pragma unroll
            for (int i = 0; i < 3; ++i)
#pragma unroll
                for (int j = 0; j < 3; ++j) {
                    int yy = y + i - 1, xx = x + j - 1;
                    uv[ic][i * 3 + j] =
                        inb(yy, xx) ? pa.u[ic * N + yy * 128 + xx] : 0.f;
                }
        float uf[5] = {0, 0, 0, 0, 0};
#pragma unroll
        for (int ic = 0; ic < 8; ++ic)
#pragma unroll
            for (int k = 0; k < 9; ++k)
#pragma unroll
                for (int o = 0; o < 5; ++o)
                    uf[o] = fmaf(uv[ic][k], pa.wnlu[(o * 8 + ic) * 9 + k], uf[o]);

        if (g == 0) {
#pragma unroll
            for (int o = 0; o < 5; ++o) {
                float a = 0, b = 0, c1 = 0;
#pragma unroll
                for (int i = 0; i < 5; ++i) {
                    a  = fmaf(pa.sphi[o * 5 + i], uf[i], a);
                    b  = fmaf(pa.sth [o * 5 + i], uf[i], b);
                    c1 = fmaf(pa.gg  [o * 5 + i], uf[i], c1);
                }
                ws[OFF_PHI2 + o * N + p] = a;
                ws[OFF_TH2  + o * N + p] = b;
                ws[OFF_G1   + o * N + p] = c1;
            }
        } else if (g == 1) {
#pragma unroll
            for (int o = 0; o < 5; ++o) {
                float c2 = 0, c3 = 0;
#pragma unroll
                for (int i = 0; i < 5; ++i) {
                    c2 = fmaf(pa.sg[o * 5 + i], uf[i], c2);
                    c3 = fmaf(pa.mg[o * 5 + i], uf[i], c3);
                }
                ws[OFF_G2 + o * N + p] = c2;
                ws[OFF_G3 + o * N + p] = c3;
            }
        } else {
            float pv[9];
#pragma unroll
            for (int i = 0; i < 3; ++i)
#pragma unroll
                for (int j = 0; j < 3; ++j) {
                    int yy = y + i - 1, xx = x + j - 1;
                    pv[i * 3 + j] = inb(yy, xx) ? pa.pan[yy * 128 + xx] : 0.f;
                }
            float pf[3] = {0, 0, 0};
#pragma unroll
            for (int k = 0; k < 9; ++k)
#pragma unroll
                for (int o = 0; o < 3; ++o)
                    pf[o] = fmaf(pv[k], pa.wnlpan[o * 9 + k], pf[o]);
            float cat[8] = {uf[0], uf[1], uf[2], uf[3], uf[4],
                            pf[0], pf[1], pf[2]};
            if (g == 2) {
#pragma unroll
                for (int o = 0; o < 3; ++o) {
                    float a = 0, b = 0;
#pragma unroll
                    for (int i = 0; i < 3; ++i) {
                        a = fmaf(pa.gphi[o * 3 + i], pf[i], a);
                        b = fmaf(pa.gth [o * 3 + i], pf[i], b);
                    }
                    ws[OFF_PHI1 + o * N + p] = a;
                    ws[OFF_TH1  + o * N + p] = b;
                }
#pragma unroll
                for (int o = 0; o < 8; ++o) {
                    float a = 0;
#pragma unroll
                    for (int i = 0; i < 8; ++i)
                        a = fmaf(pa.mphi[o * 8 + i], cat[i], a);
                    ws[OFF_PHI3 + o * N + p] = a;
                }
            } else {
#pragma unroll
                for (int o = 0; o < 8; ++o) {
                    float b = 0;
#pragma unroll
                    for (int i = 0; i < 8; ++i)
                        b = fmaf(pa.mth[o * 8 + i], cat[i], b);
                    ws[OFF_TH3 + o * N + p] = b;
                }
            }
        }
        return;
    }

    int idx = (bid - 256) * 256 + t;
    if (idx >= WPREP_TOT) return;
    if (idx < SLAB_TOT) {
        const float* W;
        int mt, ks, lane, j, ocv;
        if (idx < SLAB_RC) {
            int cv = idx / SLAB_CV, r = idx - cv * SLAB_CV;
            mt = r / 8192;  r -= mt * 8192;
            ks = r / 512;   r -= ks * 512;
            lane = r / 8;   j = r - lane * 8;
            W = pa.w[cv]; ocv = 42;
        } else {
            int r = idx - SLAB_RC;
            mt = 0;
            ks = r / 512;   r -= ks * 512;
            lane = r / 8;   j = r - lane * 8;
            W = pa.w[6]; ocv = 8;
        }
        int quad = lane >> 4, m = lane & 15;
        int g = ks * 8 + quad * 2 + (j >> 2), tx = j & 3;
        int oc = mt * 16 + m;
        u16 v = 0;
        if (g < 126 && tx < 3 && oc < ocv) {
            int ic = g / 3, ty = g - ic * 3;
            v = f2bf(W[(oc * 42 + ic) * 9 + ty * 3 + tx]);
        }
        slab[idx] = v;
        return;
    }
    idx -= SLAB_TOT;
    u16* buf = (idx < 42 * ZPB) ? xpad : fpad;
    int e = (idx < 42 * ZPB) ? idx : idx - 42 * ZPB;
    int plane = e / ZPB, rem = e - plane * ZPB;
    int row, col;
    if (rem < 136)      { row = 0;             col = rem; }
    else if (rem < 272) { row = 129;           col = rem - 136; }
    else if (rem < 400) { row = 1 + rem - 272; col = 0; }
    else if (rem < 528) { row = 1 + rem - 400; col = 129; }
    else                { row = 1 + rem - 528; col = 130; }
    buf[plane * XPLANE + row * 136 + col] = 0;
}

// ---------------------------------------------------------------------------
// K2: attention heads via MFMA (R14). Block = one 8x8 px tile, one head,
// 256 threads = 4 waves; wave w owns px rows m = w*16..w*16+15 (m=(py<<3)|px).
// Neighborhood n = r*16 + c', r in 0..13 (gy' = ty0-3+r), c' in 0..15
// (gx' = tx0-3+c'; c'>=14 is pad -> zero B rows, auto-masked by window).
// GEMM1: A-frag (thp) gathered to regs: lane m=l&15, k-slot (l>>4)*8+j.
//        B-frag (php) from LDS sB[n][k] row, 1 ds_read_b128 per (nc,kc).
// C layout: row m = (l>>4)*4+reg, col n = nc*16 + (l&15).
// Softmax over window (nc-py in [0,7) and c'-px in [0,7)) in registers,
// reduced across the 16 col-lanes via shfl_xor 1/2/4/8.
// PV: scalar o[ch] = sum_n p*g with g from LDS (broadcast reads), same
// shfl reduce; lane c'==ch (<5) writes 4 px.
// ---------------------------------------------------------------------------
template <int C, int P>
DEV void head_mfma(const float* __restrict__ phi, const float* __restrict__ theta,
                   const float* __restrict__ g, float* __restrict__ oh,
                   u16* __restrict__ sB, float* __restrict__ sG,
                   int ty0, int tx0, int t) {
    constexpr int D  = C * P * P;            // 27 / 5 / 72
    constexpr int KC = (D + 31) / 32;        // 1 / 1 / 3
    constexpr int K  = KC * 32;
    constexpr int SK = K + 8;                // padded row stride (u16)

    // ---- stage g tile [5][14*14] f32
    for (int i = t; i < 5 * 196; i += 256) {
        int c = i / 196, rem = i - c * 196;
        int r = rem / 14, cc = rem - r * 14;
        int gy = ty0 - 3 + r, gx = tx0 - 3 + cc;
        sG[i] = inb(gy, gx) ? g[c * N + gy * 128 + gx] : 0.f;
    }

    // ---- im2col php -> sB[n][k] (one thread per n)
    if (t < 224) {
        int r = t >> 4, cc = t & 15;
        int gy0 = ty0 - 3 + r, gx0 = tx0 - 3 + cc;
        union { uint4 u[K / 8]; u16 s[K]; } rb;
#pragma unroll
        for (int k = 0; k < K; ++k) {
            float v = 0.f;
            if (cc < 14 && k < D) {
                int c, dy, dx;
                if (P == 3) {
                    c = k / 9; int tau = k - c * 9;
                    dy = tau / 3 - 1; dx = tau - (tau / 3) * 3 - 1;
                } else { c = k; dy = 0; dx = 0; }
                int yy = gy0 + dy, xx = gx0 + dx;
                v = inb(yy, xx) ? phi[c * N + yy * 128 + xx] : 0.f;
            }
            rb.s[k] = f2bf(v);
        }
        u16* dst = sB + t * SK;
#pragma unroll
        for (int q = 0; q < K / 8; ++q)
            *(uint4*)(dst + q * 8) = rb.u[q];
    }

    // ---- gather thp A-fragments to registers
    const int lane = t & 63, wave = t >> 6;
    const int og = lane >> 4, cp = lane & 15;
    {
    }
    const int mA = wave * 16 + cp;
    const int gyA = ty0 + (mA >> 3), gxA = tx0 + (mA & 7);
    union ABu { uint4 u; u16 s[8]; bf16x8 b; };
    ABu afr[KC];
#pragma unroll
    for (int kc = 0; kc < KC; ++kc)
#pragma unroll
        for (int j = 0; j < 8; ++j) {
            int k = kc * 32 + og * 8 + j;
            float v = 0.f;
            if (k < D) {
                int c, dy, dx;
                if (P == 3) {
                    c = k / 9; int tau = k - c * 9;
                    dy = tau / 3 - 1; dx = tau - (tau / 3) * 3 - 1;
                } else { c = k; dy = 0; dx = 0; }
                int yy = gyA + dy, xx = gxA + dx;
                v = inb(yy, xx) ? theta[c * N + yy * 128 + xx] : 0.f;
            }
            afr[kc].s[j] = f2bf(v);
        }
    __syncthreads();

    // ---- GEMM1: S[m][n]
    f32x4 acc[14];
#pragma unroll
    for (int nc = 0; nc < 14; ++nc) acc[nc] = (f32x4){0.f, 0.f, 0.f, 0.f};
    const u16* sBl = sB + cp * SK + og * 8;
#pragma unroll
    for (int nc = 0; nc < 14; ++nc)
#pragma unroll
        for (int kc = 0; kc < KC; ++kc) {
            ABu bf_;
            bf_.u = *(const uint4*)(sBl + nc * 16 * SK + kc * 32);
            acc[nc] = __builtin_amdgcn_mfma_f32_16x16x32_bf16(
                afr[kc].b, bf_.b, acc[nc], 0, 0, 0);
        }

    // ---- softmax in C-layout regs
    float mx[4], sum[4];
#pragma unroll
    for (int reg = 0; reg < 4; ++reg) {
        int midx = wave * 16 + og * 4 + reg;
        int py = midx >> 3, px = midx & 7;
        bool colok = (unsigned)(cp - px) < 7u;
        float m0 = -3.0e38f;
#pragma unroll
        for (int nc = 0; nc < 14; ++nc) {
            bool valid = colok && (unsigned)(nc - py) < 7u;
            if (valid) m0 = fmaxf(m0, acc[nc][reg]);
        }
        mx[reg] = m0;
    }
#pragma unroll
    for (int reg = 0; reg < 4; ++reg) {
        mx[reg] = fmaxf(mx[reg], __shfl_xor(mx[reg], 1));
        mx[reg] = fmaxf(mx[reg], __shfl_xor(mx[reg], 2));
        mx[reg] = fmaxf(mx[reg], __shfl_xor(mx[reg], 4));
        mx[reg] = fmaxf(mx[reg], __shfl_xor(mx[reg], 8));
    }
#pragma unroll
    for (int reg = 0; reg < 4; ++reg) {
        int midx = wave * 16 + og * 4 + reg;
        int py = midx >> 3, px = midx & 7;
        bool colok = (unsigned)(cp - px) < 7u;
        float s0 = 0.f;
#pragma unroll
        for (int nc = 0; nc < 14; ++nc) {
            bool valid = colok && (unsigned)(nc - py) < 7u;
            float e = valid ? __expf(acc[nc][reg] - mx[reg]) : 0.f;
            acc[nc][reg] = e;
            s0 += e;
        }
        sum[reg] = s0;
    }
#pragma unroll
    for (int reg = 0; reg < 4; ++reg) {
        sum[reg] += __shfl_xor(sum[reg], 1);
        sum[reg] += __shfl_xor(sum[reg], 2);
        sum[reg] += __shfl_xor(sum[reg], 4);
        sum[reg] += __shfl_xor(sum[reg], 8);
    }

    // ---- PV (scalar, g broadcast from LDS)
    float o0[5][4];
#pragma unroll
    for (int ch = 0; ch < 5; ++ch)
#pragma unroll
        for (int reg = 0; reg < 4; ++reg) o0[ch][reg] = 0.f;
#pragma unroll
    for (int ch = 0; ch < 5; ++ch)
#pragma unroll
        for (int nc = 0; nc < 14; ++nc) {
            float gvv = (cp < 14) ? sG[ch * 196 + nc * 14 + cp] : 0.f;
#pragma unroll
            for (int reg = 0; reg < 4; ++reg)
                o0[ch][reg] = fmaf(acc[nc][reg], gvv, o0[ch][reg]);
        }
#pragma unroll
    for (int ch = 0; ch < 5; ++ch)
#pragma unroll
        for (int reg = 0; reg < 4; ++reg) {
            o0[ch][reg] += __shfl_xor(o0[ch][reg], 1);
            o0[ch][reg] += __shfl_xor(o0[ch][reg], 2);
            o0[ch][reg] += __shfl_xor(o0[ch][reg], 4);
            o0[ch][reg] += __shfl_xor(o0[ch][reg], 8);
        }

    if (cp < 5) {
        float inv[4];
#pragma unroll
        for (int reg = 0; reg < 4; ++reg) inv[reg] = 1.f / sum[reg];
#pragma unroll
        for (int ch = 0; ch < 5; ++ch)
            if (cp == ch) {
#pragma unroll
                for (int reg = 0; reg < 4; ++reg) {
                    int midx = wave * 16 + og * 4 + reg;
                    int gy = ty0 + (midx >> 3), gx = tx0 + (midx & 7);
                    oh[ch * N + gy * 128 + gx] = o0[ch][reg] * inv[reg];
                }
            }
    }
}

__global__ __launch_bounds__(256) void heads_k(float* __restrict__ ws) {
    __shared__ u16 smem[25256];          // sB 224*104 u16 + sG 980 f32 = 50512B
    u16* sB = smem;
    float* sG = (float*)(smem + 23296);
    const int t = threadIdx.x;
    const int ty0 = (blockIdx.x >> 4) * 8, tx0 = (blockIdx.x & 15) * 8;
    if (blockIdx.y == 0)
        head_mfma<3, 3>(ws + OFF_PHI1, ws + OFF_TH1, ws + OFF_G1, ws + OFF_OH1,
                        sB, sG, ty0, tx0, t);
    else if (blockIdx.y == 1)
        head_mfma<5, 1>(ws + OFF_PHI2, ws + OFF_TH2, ws + OFF_G2, ws + OFF_OH2,
                        sB, sG, ty0, tx0, t);
    else
        head_mfma<8, 3>(ws + OFF_PHI3, ws + OFF_TH3, ws + OFF_G3, ws + OFF_OH3,
                        sB, sG, ty0, tx0, t);
}

// ---------------------------------------------------------------------------
// K3: assemble, grid (64, 5). Writes x f32 (skip) + padded bf16 (MFMA input).
// ---------------------------------------------------------------------------
__global__ __launch_bounds__(256, 2) void assemble_k(
    const float* __restrict__ u, const float* __restrict__ pan,
    const float* __restrict__ wres, const float* __restrict__ wrp,
    const float* __restrict__ mlpw, const float* __restrict__ mlpb,
    float* __restrict__ ws, u16* __restrict__ xpad) {
    const int p = blockIdx.x * 256 + threadIdx.x;
    const int y = p >> 7, x = p & 127;
    const int padp = (y + 1) * 136 + (x + 1);
    float* xb = ws + OFF_X;

    if (blockIdx.y == 0) {
        const float w0 = mlpw[0], w1 = mlpw[1], w2 = mlpw[2];
        const float bb = mlpb[0];
#pragma unroll
        for (int c = 0; c < 5; ++c) {
            float a = ws[OFF_OH1 + c * N + p] * w0 +
                      ws[OFF_OH2 + c * N + p] * w1 +
                      ws[OFF_OH3 + c * N + p] * w2 + bb;
            xb[c * N + p] = a;
            xpad[c * XPLANE + padp] = f2bf(a);
        }
        float pv[9];
#pragma unroll
        for (int i = 0; i < 3; ++i)
#pragma unroll
            for (int j = 0; j < 3; ++j) {
                int yy = y + i - 1, xx = x + j - 1;
                pv[i * 3 + j] = inb(yy, xx) ? pan[yy * 128 + xx] : 0.f;
            }
        float a5[5] = {0, 0, 0, 0, 0};
#pragma unroll
        for (int k = 0; k < 9; ++k)
#pragma unroll
            for (int o = 0; o < 5; ++o)
                a5[o] = fmaf(pv[k], wrp[o * 9 + k], a5[o]);
#pragma unroll
        for (int o = 0; o < 5; ++o) {
            xb[(37 + o) * N + p] = a5[o];
            xpad[(37 + o) * XPLANE + padp] = f2bf(a5[o]);
        }
    } else {
        const int ob = (blockIdx.y - 1) * 8;
        float uv[8][9];
#pragma unroll
        for (int ic = 0; ic < 8; ++ic)
#pragma unroll
            for (int i = 0; i < 3; ++i)
#pragma unroll
                for (int j = 0; j < 3; ++j) {
                    int yy = y + i - 1, xx = x + j - 1;
                    uv[ic][i * 3 + j] =
                        inb(yy, xx) ? u[ic * N + yy * 128 + xx] : 0.f;
                }
        float acc[8] = {0, 0, 0, 0, 0, 0, 0, 0};
#pragma unroll
        for (int ic = 0; ic < 8; ++ic)
#pragma unroll
            for (int k = 0; k < 9; ++k)
#pragma unroll
                for (int o = 0; o < 8; ++o)
                    acc[o] = fmaf(uv[ic][k], wres[((ob + o) * 8 + ic) * 9 + k],
                                  acc[o]);
#pragma unroll
        for (int o = 0; o < 8; ++o) {
            xb[(5 + ob + o) * N + p] = acc[o];
            xpad[(5 + ob + o) * XPLANE + padp] = f2bf(acc[o]);
        }
    }
}

// ---------------------------------------------------------------------------
// K4: implicit-GEMM conv on MFMA, padded bf16 input. R14: block = 16 px of
// one row, 192 threads = 3 waves (wave = oc-tile mt). Grid 1024 ->
// 4 blocks/CU (launch_bounds(192,3)). Pair-dword LDS tile [128 g-rows][24],
// B-frag = 4 ds_read_b32 at {0,2,24,26} + ks*192 + quad*48 + col.
// ---------------------------------------------------------------------------
template <bool SKIP, bool WF32, bool WPAD>
__global__ __launch_bounds__(192, 3) void convm_k(
    const u16* __restrict__ xin, const u16* __restrict__ slab,
    const float* __restrict__ bs, const float* __restrict__ skip,
    float* __restrict__ of32, u16* __restrict__ opad) {
    __shared__ __align__(16) u32 sXp[3072];   // 128 rows x 24 pair-dwords
    const int t = threadIdx.x;
    const int y = blockIdx.x >> 3, x0 = (blockIdx.x & 7) << 4;

    const u16* srcbase = xin + y * 136 + x0;   // pad rows y..y+2 = img y-1..y+1
#pragma unroll
    for (int it = 0; it < 2; ++it) {
        int c = it * 192 + t;
        if (c < 378) {                         // 126 rows * 3 slots
            int row = c / 3, slot = c - row * 3;
            int ic = row / 3, r = row - ic * 3;
            const u16* sp = srcbase + ic * XPLANE + r * 136 + slot * 8;
            uint4 v = *(const uint4*)sp;
            u32 nxt = (slot < 2) ? (u32)sp[8] : 0u;
            u32 d0 = v.x, d1 = v.y, d2 = v.z, d3 = v.w;
            uint4 w0, w1;
            w0.x = d0; w0.y = (d0 >> 16) | (d1 << 16);
            w0.z = d1; w0.w = (d1 >> 16) | (d2 << 16);
            w1.x = d2; w1.y = (d2 >> 16) | (d3 << 16);
            w1.z = d3; w1.w = (d3 >> 16) | (nxt << 16);
            u32* dst = sXp + row * 24 + slot * 8;
            *(uint4*)dst = w0;
            *(uint4*)(dst + 4) = w1;
        }
    }
    if (t < 48) sXp[3024 + t] = 0;             // g=126,127 pad rows
    __syncthreads();

    const int lane = t & 63, mt = t >> 6;
    const int quad = lane >> 4, col = lane & 15;

    union AB { uint4 u; bf16x8 b; };
    AB a[16];
#pragma unroll
    for (int ks = 0; ks < 16; ++ks)
        a[ks].u = ((const uint4*)slab)[(mt * 16 + ks) * 64 + lane];

    const u32* bb = sXp + quad * 48 + col;
    f32x4 acc = {0.f, 0.f, 0.f, 0.f};
#pragma unroll
    for (int ks = 0; ks < 16; ++ks) {
        union { uint4 u; bf16x8 b; } bv;
        const u32* pb = bb + ks * 192;
        bv.u.x = pb[0]; bv.u.y = pb[2]; bv.u.z = pb[24]; bv.u.w = pb[26];
        acc = __builtin_amdgcn_mfma_f32_16x16x32_bf16(a[ks].b, bv.b, acc,
                                                      0, 0, 0);
    }

    const int xg = x0 + col;
    const int px = y * 128 + xg;
    const int padp = (y + 1) * 136 + (xg + 1);
#pragma unroll
    for (int reg = 0; reg < 4; ++reg) {
        int oc = mt * 16 + quad * 4 + reg;
        if (oc < 42) {
            float v = acc[reg] + bs[oc];
            if (SKIP) v += skip[oc * N + px];
            v = fmaxf(v, 0.f);
            if (WF32) of32[oc * N + px] = v;
            if (WPAD) opad[oc * XPLANE + padp] = f2bf(v);
        }
    }
}

// ---------------------------------------------------------------------------
// K5: recon conv 42->8, padded bf16 input, 32-px strips (grid 512, 128 thr).
// Pair-dword scheme, stride 40, mt=0.
// ---------------------------------------------------------------------------
__global__ __launch_bounds__(128, 1) void convr_k(
    const u16* __restrict__ xin, const u16* __restrict__ slab,
    float* __restrict__ out) {
    __shared__ __align__(16) u32 sXp[5120];
    const int t = threadIdx.x;
    const int y = blockIdx.x >> 2, x0 = (blockIdx.x & 3) << 5;

    const u16* srcbase = xin + y * 136 + x0;
#pragma unroll
    for (int it = 0; it < 5; ++it) {
        int c = it * 128 + t;
        if (c < 630) {
            int row = c / 5, slot = c - row * 5;
            int ic = row / 3, r = row - ic * 3;
            const u16* sp = srcbase + ic * XPLANE + r * 136 + slot * 8;
            uint4 v = *(const uint4*)sp;
            u32 nxt = sp[8];
            u32 d0 = v.x, d1 = v.y, d2 = v.z, d3 = v.w;
            uint4 w0, w1;
            w0.x = d0; w0.y = (d0 >> 16) | (d1 << 16);
            w0.z = d1; w0.w = (d1 >> 16) | (d2 << 16);
            w1.x = d2; w1.y = (d2 >> 16) | (d3 << 16);
            w1.z = d3; w1.w = (d3 >> 16) | (nxt << 16);
            u32* dst = sXp + row * 40 + slot * 8;
            *(uint4*)dst = w0;
            *(uint4*)(dst + 4) = w1;
        }
    }
    if (t < 80) sXp[5040 + t] = 0;
    __syncthreads();

    const int lane = t & 63, wave = t >> 6;
    const int quad = lane >> 4, col = lane & 15;
    const int ncol = wave * 16 + col;

    union AB { uint4 u; bf16x8 b; };
    AB a[16];
#pragma unroll
    for (int ks = 0; ks < 16; ++ks)
        a[ks].u = ((const uint4*)slab)[ks * 64 + lane];

    const u32* bb = sXp + quad * 80 + ncol;
    f32x4 acc = {0.f, 0.f, 0.f, 0.f};
#pragma unroll
    for (int ks = 0; ks < 16; ++ks) {
        union { uint4 u; bf16x8 b; } bv;
        const u32* pb = bb + ks * 320;
        bv.u.x = pb[0]; bv.u.y = pb[2]; bv.u.z = pb[40]; bv.u.w = pb[42];
        acc = __builtin_amdgcn_mfma_f32_16x16x32_bf16(a[ks].b, bv.b, acc,
                                                      0, 0, 0);
    }
    const int px = y * 128 + x0 + ncol;
#pragma unroll
    for (int reg = 0; reg < 4; ++reg) {
        int oc = quad * 4 + reg;
        if (oc < 8) out[oc * N + px] = acc[reg];
    }
}

// ---------------------------------------------------------------------------
extern "C" void kernel_launch(void* const* d_in, const int* in_sizes, int n_in,
                              void* d_out, int out_size, void* d_ws, size_t ws_size,
                              hipStream_t stream) {
    (void)in_sizes; (void)n_in; (void)out_size; (void)ws_size;
    float* ws = (float*)d_ws;
    float* out = (float*)d_out;

    PrepArgs pa;
    pa.u      = (const float*)d_in[0];
    pa.pan    = (const float*)d_in[1];
    pa.wnlu   = (const float*)d_in[2];
    pa.wnlpan = (const float*)d_in[3];
    pa.gphi   = (const float*)d_in[4];
    pa.gth    = (const float*)d_in[5];
    pa.gg     = (const float*)d_in[6];
    pa.sphi   = (const float*)d_in[7];
    pa.sth    = (const float*)d_in[8];
    pa.sg     = (const float*)d_in[9];
    pa.mphi   = (const float*)d_in[10];
    pa.mth    = (const float*)d_in[11];
    pa.mg     = (const float*)d_in[12];
    pa.w[0]   = (const float*)d_in[18];
    pa.w[1]   = (const float*)d_in[20];
    pa.w[2]   = (const float*)d_in[22];
    pa.w[3]   = (const float*)d_in[24];
    pa.w[4]   = (const float*)d_in[26];
    pa.w[5]   = (const float*)d_in[28];
    pa.w[6]   = (const float*)d_in[17];   // recon

    const float* mlpw = (const float*)d_in[13];
    const float* mlpb = (const float*)d_in[14];
    const float* wres = (const float*)d_in[15];
    const float* wrp  = (const float*)d_in[16];

    u16* xpad = (u16*)(ws + OFF_XPAD);
    u16* fpad = (u16*)(ws + OFF_FPAD);
    u16* slab = (u16*)(ws + OFF_SLAB);

    prep_k<<<256 + WPREP_BLK, 256, 0, stream>>>(pa, ws, slab, xpad, fpad);
    heads_k<<<dim3(256, 3), 256, 0, stream>>>(ws);
    assemble_k<<<dim3(64, 5), 256, 0, stream>>>(pa.u, pa.pan, wres, wrp, mlpw,
                                                mlpb, ws, xpad);

    for (int r = 0; r < 3; ++r) {
        const float* b1 = (const float*)d_in[19 + 4 * r];
        const float* b2 = (const float*)d_in[21 + 4 * r];
        convm_k<false, false, true>
            <<<1024, 192, 0, stream>>>(xpad, slab + (2 * r) * SLAB_CV, b1,
                                       nullptr, nullptr, fpad);
        convm_k<true, true, true>
            <<<1024, 192, 0, stream>>>(fpad, slab + (2 * r + 1) * SLAB_CV, b2,
                                       ws + OFF_X, ws + OFF_X, xpad);
    }
    convr_k<<<512, 128, 0, stream>>>(xpad, slab + SLAB_RC, out);
}